// Round 1
// 465.190 us; speedup vs baseline: 1.0703x; 1.0703x over previous
//
#include <hip/hip_runtime.h>
#include <cmath>

typedef __attribute__((ext_vector_type(8))) _Float16 half8;
typedef __attribute__((ext_vector_type(8))) unsigned short ushort8;
typedef __attribute__((ext_vector_type(4))) float f32x4;

#define HH 7168
#define NE 256
#define NQ 224        // K32 chunks
#define NITER 56      // BK=128 iterations
#define TOPK 8
#define TOPKG 4
#define WSC 1024.f
#define INV_WS (1.f/1024.f)
#define C1 (1.f/2048.f)       // 2^-11
#define C2 (1.f/4194304.f)    // 2^-22

// 2-level f16 split: x = h + m*2^-11, residual ~2^-25|x|
__device__ __forceinline__ void split2(float x, unsigned short& h, unsigned short& m){
  const _Float16 hh = (_Float16)x;
  const float r = x - (float)hh;                 // exact
  const _Float16 mm = (_Float16)(r * 2048.f);
  h = __builtin_bit_cast(unsigned short, hh);
  m = __builtin_bit_cast(unsigned short, mm);
}

// W*1024 -> (h,m) f16 in MFMA B-fragment order, coalesced writes.
// slot(q,nt,L) holds B[k=32q+8(L>>4)+j][e=16nt+(L&15)], j=0..7.
__global__ __launch_bounds__(256) void prep_w(const float* __restrict__ wgt,
                                              unsigned short* __restrict__ bh,
                                              unsigned short* __restrict__ bm){
  const int b = blockIdx.x;                 // 896 = 16 nt * 56 q-groups
  const int nt = b & 15, qb = (b >> 4) * 4;
  const int w = threadIdx.x >> 6, L = threadIdx.x & 63;
  const int q = qb + w;
  const int e = nt*16 + (L & 15);
  const int k0 = 32*q + 8*(L >> 4);
  const float4 a0 = *(const float4*)(wgt + (size_t)e*HH + k0);
  const float4 a1 = *(const float4*)(wgt + (size_t)e*HH + k0 + 4);
  const float v[8] = {a0.x,a0.y,a0.z,a0.w,a1.x,a1.y,a1.z,a1.w};
  ushort8 h8, m8;
#pragma unroll
  for(int j=0;j<8;j++){ unsigned short hh,mm; split2(v[j]*WSC, hh, mm); h8[j]=hh; m8[j]=mm; }
  const size_t base = ((size_t)(q*16+nt)*64 + L)*8;
  *(ushort8*)(bh+base) = h8;
  *(ushort8*)(bm+base) = m8;
}

// GEMM: block = 32 tokens x 128 experts (slice), 512 thr / 8 waves,
// wave tile = 16 tok x 32 exp (mtp in {0,1}, ntp in 0..3, 2 ntl).
// Grid 512 -> 2 blocks/CU (16 waves/CU, 4/SIMD) vs previous 1 block/CU.
// A-LDS XOR-swizzled so staging ds_write_b128 is bank-conflict-free.
// XCD swizzle: slice=(b>>2)&1 keeps each 3.67MB B-slice L2-resident on its 4 XCDs.
#define ABYTE(buf,lvl,mt,q,row) (((((buf)*2+(lvl))*8 + (mt)*4 + (q))*64 + (row))*16)
__device__ __forceinline__ int swz(int bo){ return bo ^ (((bo >> 8) & 7) << 4); }

__global__ __launch_bounds__(512,4)
void gemm(const float* __restrict__ hs,
          const unsigned short* __restrict__ bhp,
          const unsigned short* __restrict__ bmp,
          float* __restrict__ lgout){
  __shared__ __align__(16) unsigned short alds[16384];   // 32 KB: 2buf x 2lvl x 2mt x 4q x 64rows x 8
  char* const aldsb = (char*)alds;

  const int tid = threadIdx.x, lane = tid & 63, w = tid >> 6;
  const int b = blockIdx.x;
  const int slice = (b >> 2) & 1;
  const int tg = (b >> 3)*4 + (b & 3);     // 0..255
  const int tb = tg*32, eb = slice*128;
  const int mtp = w >> 2, ntp = w & 3;     // wave tile: 1 mt x 2 ntl

  const half8* __restrict__ bhv = (const half8*)bhp;
  const half8* __restrict__ bmv = (const half8*)bmp;

  f32x4 ksum[2], kcmp[2];
#pragma unroll
  for(int c=0;c<2;c++){ ksum[c]=f32x4{0,0,0,0}; kcmp[c]=f32x4{0,0,0,0}; }

  // staging: thread -> token tid>>4 (16 thr/token), 8 ks at (tid&15)*8
  const int tokS = tid >> 4, kidx = tid & 15;
  const int mtS = tokS >> 4, m16S = tokS & 15;
  const int qS = kidx >> 2, kgS = kidx & 3;
  const int rowS = kgS*16 + m16S;
  const float* agp = hs + (size_t)(tb + tokS)*HH + kidx*8;

  float4 ga[2];
  ga[0] = *(const float4*)(agp);
  ga[1] = *(const float4*)(agp + 4);

  auto stage = [&](int buf){
    unsigned short h[8], m[8];
    const float* gv = (const float*)ga;
#pragma unroll
    for(int p=0;p<8;p++) split2(gv[p], h[p], m[p]);
    ushort8 h8, m8;
#pragma unroll
    for(int j=0;j<8;j++){ h8[j]=h[j]; m8[j]=m[j]; }
    *(ushort8*)(aldsb + swz(ABYTE(buf,0,mtS,qS,rowS))) = h8;
    *(ushort8*)(aldsb + swz(ABYTE(buf,1,mtS,qS,rowS))) = m8;
  };

  stage(0);
  half8 Bh[2], Bm[2];
#pragma unroll
  for(int ntl=0;ntl<2;ntl++){
    const int slot = ((0*16 + slice*8 + ntp*2 + ntl)*64 + lane);
    Bh[ntl] = bhv[slot]; Bm[ntl] = bmv[slot];
  }
  __syncthreads();

  for(int i=0;i<NITER;i++){
    const int cur = i & 1, nb = cur ^ 1;
    if(i+1 < NITER){
      const float* ap = agp + (size_t)(i+1)*128;
      ga[0] = *(const float4*)(ap);
      ga[1] = *(const float4*)(ap + 4);
    }
    f32x4 c0[2], c1[2], c2[2];
#pragma unroll
    for(int c=0;c<2;c++){ c0[c]=f32x4{0,0,0,0}; c1[c]=f32x4{0,0,0,0}; c2[c]=f32x4{0,0,0,0}; }

#pragma unroll
    for(int s=0;s<4;s++){
      const int q = i*4 + s;
      const half8 ah = *(const half8*)(aldsb + swz(ABYTE(cur,0,mtp,s,lane)));
      const half8 am = *(const half8*)(aldsb + swz(ABYTE(cur,1,mtp,s,lane)));
      half8 BhN[2], BmN[2];
      const bool more = (q+1 < NQ);
      if(more){
#pragma unroll
        for(int ntl=0;ntl<2;ntl++){
          const int slot = (((q+1)*16 + slice*8 + ntp*2 + ntl)*64 + lane);
          BhN[ntl] = bhv[slot]; BmN[ntl] = bmv[slot];
        }
      }
#pragma unroll
      for(int ntl=0;ntl<2;ntl++){
        c0[ntl] = __builtin_amdgcn_mfma_f32_16x16x32_f16(ah, Bh[ntl], c0[ntl], 0,0,0);
        c1[ntl] = __builtin_amdgcn_mfma_f32_16x16x32_f16(ah, Bm[ntl], c1[ntl], 0,0,0);
        c1[ntl] = __builtin_amdgcn_mfma_f32_16x16x32_f16(am, Bh[ntl], c1[ntl], 0,0,0);
        c2[ntl] = __builtin_amdgcn_mfma_f32_16x16x32_f16(am, Bm[ntl], c2[ntl], 0,0,0);
      }
      if(more){
#pragma unroll
        for(int ntl=0;ntl<2;ntl++){ Bh[ntl]=BhN[ntl]; Bm[ntl]=BmN[ntl]; }
      }
    }
    if(i+1 < NITER) stage(nb);
    // Kahan flush of this 128-k window
#pragma unroll
    for(int c=0;c<2;c++)
#pragma unroll
      for(int r=0;r<4;r++){
        const float v = c0[c][r] + c1[c][r]*C1 + c2[c][r]*C2;
        const float y = v - kcmp[c][r];
        const float t = ksum[c][r] + y;
        kcmp[c][r] = (t - ksum[c][r]) - y;
        ksum[c][r] = t;
      }
    __syncthreads();
  }

  // epilogue: C layout col=lane&15 (expert), row=(lane>>4)*4+r (token); undo W scale
#pragma unroll
  for(int ntl=0;ntl<2;ntl++)
#pragma unroll
    for(int r=0;r<4;r++){
      const int tok = mtp*16 + (lane>>4)*4 + r;
      const int e = (ntp*2+ntl)*16 + (lane&15);
      const float lg = (ksum[ntl][r] - kcmp[ntl][r]) * INV_WS;
      lgout[(size_t)(tb+tok)*NE + eb + e] = lg;
    }
}

// Gating (R1/R4-verified flow), reading logits from global scratch.
// 1 token per wave, grid T/4: 8 blocks/CU so the serial shuffle chains overlap.
__global__ __launch_bounds__(256)
void gate(const float* __restrict__ lg, const float* __restrict__ bias,
          float* __restrict__ out, int T){
  const int tid = threadIdx.x, lane = tid & 63, wv = tid >> 6;
  const int t = blockIdx.x*4 + wv;
  const float4 bias4 = *(const float4*)(bias + 4*lane);
  const int g = lane >> 3;
  const float NEG_INF = -__builtin_inff();

  const float4 l4 = *(const float4*)(lg + (size_t)t*NE + 4*lane);
  float4 r4;   // uncorrected sigmoid scores
  r4.x = 1.f/(1.f + expf(-l4.x));
  r4.y = 1.f/(1.f + expf(-l4.y));
  r4.z = 1.f/(1.f + expf(-l4.z));
  r4.w = 1.f/(1.f + expf(-l4.w));
  float4 s4;   // corrected
  s4.x = r4.x + bias4.x; s4.y = r4.y + bias4.y;
  s4.z = r4.z + bias4.z; s4.w = r4.w + bias4.w;

  float m1 = s4.x, m2 = NEG_INF;
  if (s4.y > m1) { m2 = m1; m1 = s4.y; } else if (s4.y > m2) m2 = s4.y;
  if (s4.z > m1) { m2 = m1; m1 = s4.z; } else if (s4.z > m2) m2 = s4.z;
  if (s4.w > m1) { m2 = m1; m1 = s4.w; } else if (s4.w > m2) m2 = s4.w;
#pragma unroll
  for (int m = 1; m <= 4; m <<= 1) {
    const float o1 = __shfl_xor(m1, m);
    const float o2 = __shfl_xor(m2, m);
    const float nm1 = fmaxf(m1, o1);
    const float nm2 = fmaxf(fminf(m1, o1), fmaxf(m2, o2));
    m1 = nm1; m2 = nm2;
  }
  const float gs = m1 + m2;

  float gsv[8];
#pragma unroll
  for (int j = 0; j < 8; ++j) gsv[j] = __shfl(gs, j * 8);

  unsigned gm = 0;
#pragma unroll
  for (int r = 0; r < TOPKG; ++r) {
    float best = NEG_INF; int bj = 0;
#pragma unroll
    for (int j = 0; j < 8; ++j) {
      const bool avail = !((gm >> j) & 1u);
      if (avail && gsv[j] > best) { best = gsv[j]; bj = j; }
    }
    gm |= 1u << bj;
  }
  const bool allowed = (gm >> g) & 1u;

  float v0 = allowed ? s4.x : 0.f;
  float v1 = allowed ? s4.y : 0.f;
  float v2 = allowed ? s4.z : 0.f;
  float v3 = allowed ? s4.w : 0.f;

  float sumw = 0.f;
  int myidx = 0; float myraw = 0.f;
#pragma unroll
  for (int r = 0; r < TOPK; ++r) {
    float bv = v0; int bj = 0;
    if (v1 > bv) { bv = v1; bj = 1; }
    if (v2 > bv) { bv = v2; bj = 2; }
    if (v3 > bv) { bv = v3; bj = 3; }
    int bidx = 4 * lane + bj;
#pragma unroll
    for (int m = 1; m < 64; m <<= 1) {
      const float ov = __shfl_xor(bv, m);
      const int   oi = __shfl_xor(bidx, m);
      if (ov > bv || (ov == bv && oi < bidx)) { bv = ov; bidx = oi; }
    }
    const int oj = bidx & 3;
    const float cand = (oj == 0) ? r4.x
                     : (oj == 1) ? r4.y
                     : (oj == 2) ? r4.z
                     :             r4.w;
    const float raw = __shfl(cand, bidx >> 2);
    sumw += raw;
    if (lane == r) { myidx = bidx; myraw = raw; }
    if (lane == (bidx >> 2)) {
      if      (oj == 0) v0 = NEG_INF;
      else if (oj == 1) v1 = NEG_INF;
      else if (oj == 2) v2 = NEG_INF;
      else              v3 = NEG_INF;
    }
  }

  if (lane < TOPK) {
    out[(size_t)t * TOPK + lane] = (float)myidx;
    out[(size_t)T * TOPK + (size_t)t * TOPK + lane] = myraw / (sumw + 1e-20f) * 2.5f;
  }
}

extern "C" void kernel_launch(void* const* d_in, const int* in_sizes, int n_in,
                              void* d_out, int out_size, void* d_ws, size_t ws_size,
                              hipStream_t stream) {
  const float* hs   = (const float*)d_in[0];
  const float* wgt  = (const float*)d_in[1];
  const float* bias = (const float*)d_in[2];
  float* out = (float*)d_out;

  const int T = in_sizes[0] / HH;   // 8192

  unsigned short* bh = (unsigned short*)d_ws;
  unsigned short* bm = bh + (size_t)NE*HH;
  float* lgbuf = (float*)(bm + (size_t)NE*HH);   // 8.4 MB; total ws use 15.7 MB

  hipLaunchKernelGGL(prep_w, dim3(896), dim3(256), 0, stream, wgt, bh, bm);
  hipLaunchKernelGGL(gemm,   dim3(512), dim3(512), 0, stream, hs, bh, bm, lgbuf);
  hipLaunchKernelGGL(gate,   dim3(T/4), dim3(256), 0, stream, lgbuf, bias, out, T);
}

// Round 2
// 457.656 us; speedup vs baseline: 1.0879x; 1.0165x over previous
//
#include <hip/hip_runtime.h>
#include <cmath>

typedef __attribute__((ext_vector_type(8))) _Float16 half8;
typedef __attribute__((ext_vector_type(8))) unsigned short ushort8;
typedef __attribute__((ext_vector_type(4))) float f32x4;

#define HH 7168
#define NE 256
#define NQ 224        // K32 chunks
#define NITER 112     // BK=64 iterations
#define TOPK 8
#define TOPKG 4
#define WSC 1024.f
#define INV_WS (1.f/1024.f)
#define C1 (1.f/2048.f)       // 2^-11
#define C2 (1.f/4194304.f)    // 2^-22

// 2-level f16 split: x = h + m*2^-11, residual ~2^-25|x|
__device__ __forceinline__ void split2(float x, unsigned short& h, unsigned short& m){
  const _Float16 hh = (_Float16)x;
  const float r = x - (float)hh;                 // exact
  const _Float16 mm = (_Float16)(r * 2048.f);
  h = __builtin_bit_cast(unsigned short, hh);
  m = __builtin_bit_cast(unsigned short, mm);
}

// W*1024 -> (h,m) f16 in MFMA B-fragment order, coalesced writes.
// slot(q,nt,L) holds B[k=32q+8(L>>4)+j][e=16nt+(L&15)], j=0..7.
__global__ __launch_bounds__(256) void prep_w(const float* __restrict__ wgt,
                                              unsigned short* __restrict__ bh,
                                              unsigned short* __restrict__ bm){
  const int b = blockIdx.x;                 // 896 = 16 nt * 56 q-groups
  const int nt = b & 15, qb = (b >> 4) * 4;
  const int w = threadIdx.x >> 6, L = threadIdx.x & 63;
  const int q = qb + w;
  const int e = nt*16 + (L & 15);
  const int k0 = 32*q + 8*(L >> 4);
  const float4 a0 = *(const float4*)(wgt + (size_t)e*HH + k0);
  const float4 a1 = *(const float4*)(wgt + (size_t)e*HH + k0 + 4);
  const float v[8] = {a0.x,a0.y,a0.z,a0.w,a1.x,a1.y,a1.z,a1.w};
  ushort8 h8, m8;
#pragma unroll
  for(int j=0;j<8;j++){ unsigned short hh,mm; split2(v[j]*WSC, hh, mm); h8[j]=hh; m8[j]=mm; }
  const size_t base = ((size_t)(q*16+nt)*64 + L)*8;
  *(ushort8*)(bh+base) = h8;
  *(ushort8*)(bm+base) = m8;
}

// ---------------- GEMM ----------------
// Block = 32 tok x 128 exp (slice), 512 thr / 8 waves (2mt x 4nt), K-step 64.
// B staged to LDS via global_load_lds (16B), double-buffered, prefetched one
// FULL iteration ahead -> L2 latency decoupled from the MFMA stream and from
// register allocation (R1 lesson: compiler compacted reg-prefetch away).
// A staged by threads 0-255 (same split2+swizzled ds_write as R1, now 2 q's).
// LDS: B 2x32KB + A 2x8KB = 80KB/block -> 2 blocks/CU.
#define ABYTE(buf,lvl,mt,q,row) ((((((buf)*2+(lvl))*2+(mt))*2+(q))*64+(row))*16)
#define BBYTE(buf,lvl,q,nt) ((((buf)*4+(lvl)*2+(q))*8+(nt))<<10)
__device__ __forceinline__ int swz(int bo){ return bo ^ (((bo >> 8) & 7) << 4); }

__device__ __forceinline__ void glds16(const void* g, void* l){
  __builtin_amdgcn_global_load_lds(
      (const __attribute__((address_space(1))) unsigned int*)g,
      (__attribute__((address_space(3))) unsigned int*)l, 16, 0, 0);
}

__global__ __launch_bounds__(512,4)
void gemm(const float* __restrict__ hs,
          const unsigned short* __restrict__ bhp,
          const unsigned short* __restrict__ bmp,
          float* __restrict__ lgout){
  __shared__ __align__(16) unsigned char blds[65536];  // 2buf x 2lvl x 2q x 8nt x 1KB
  __shared__ __align__(16) unsigned char alds[16384];  // 2buf x 2lvl x 2mt x 2q x 64row x 16B

  const int tid = threadIdx.x, lane = tid & 63, w = tid >> 6;
  const int b = blockIdx.x;
  const int slice = (b >> 2) & 1;          // XCD 0-3 -> slice0, 4-7 -> slice1 (L2-resident)
  const int tg = (b >> 3)*4 + (b & 3);     // 0..255
  const int tb = tg*32, eb = slice*128;
  const int mtp = w >> 2, ntp = w & 3;

  f32x4 ksum[2], kcmp[2], c0[2], c1[2], c2[2];
#pragma unroll
  for(int c=0;c<2;c++){ ksum[c]=f32x4{0,0,0,0}; kcmp[c]=f32x4{0,0,0,0}; }

  // A staging ids (threads 0..255 only; masked so addresses stay in-range)
  const int tokS = (tid & 255) >> 3, kidx = tid & 7;
  const int mtS = tokS >> 4, m16S = tokS & 15;
  const int qS = kidx >> 2, kgS = kidx & 3;
  const int rowS = kgS*16 + m16S;
  const float* agp = hs + (size_t)(tb + tokS)*HH + kidx*8;

  auto stage = [&](int buf, const float4* g){
    unsigned short h[8], m[8];
    const float* gv = (const float*)g;
#pragma unroll
    for(int p=0;p<8;p++) split2(gv[p], h[p], m[p]);
    ushort8 h8, m8;
#pragma unroll
    for(int j=0;j<8;j++){ h8[j]=h[j]; m8[j]=m[j]; }
    *(ushort8*)&alds[swz(ABYTE(buf,0,mtS,qS,rowS))] = h8;
    *(ushort8*)&alds[swz(ABYTE(buf,1,mtS,qS,rowS))] = m8;
  };

  // B staging: 32 slots (2lvl x 2q x 8nt) of 1KB, 4 per wave, wave-uniform LDS dest.
  auto bstage = [&](int buf, int q32base){
#pragma unroll
    for(int j=0;j<4;j++){
      const int sid = w*4 + j;
      const int lvl = sid >> 4, q = (sid >> 3) & 1, nt = sid & 7;
      const int q32 = q32base + q;
      const unsigned short* src = (lvl ? bmp : bhp)
          + ((size_t)((q32*16 + slice*8 + nt)*64 + lane))*8;
      glds16(src, &blds[BBYTE(buf,lvl,q,nt)]);
    }
  };

  // prologue: A0 + B0 into buf 0
  float4 ga[2];
  if(tid < 256){
    ga[0] = *(const float4*)(agp);
    ga[1] = *(const float4*)(agp + 4);
  }
  bstage(0, 0);
  if(tid < 256) stage(0, ga);
  __syncthreads();

  for(int i=0;i<NITER;i++){
    const int cur = i & 1, nb = cur ^ 1;
    const bool more = (i+1 < NITER);
    if(more){
      if(tid < 256){
        const float* ap = agp + (size_t)(i+1)*64;
        ga[0] = *(const float4*)(ap);
        ga[1] = *(const float4*)(ap + 4);
      }
      bstage(nb, 2*(i+1));                 // B for iter i+1, in flight across this iter
    }
    if((i & 1) == 0){
#pragma unroll
      for(int c=0;c<2;c++){ c0[c]=f32x4{0,0,0,0}; c1[c]=f32x4{0,0,0,0}; c2[c]=f32x4{0,0,0,0}; }
    }
#pragma unroll
    for(int s=0;s<2;s++){
      const half8 ah = *(const half8*)&alds[swz(ABYTE(cur,0,mtp,s,lane))];
      const half8 am = *(const half8*)&alds[swz(ABYTE(cur,1,mtp,s,lane))];
      half8 Bh[2], Bm[2];
#pragma unroll
      for(int ntl=0;ntl<2;ntl++){
        Bh[ntl] = *(const half8*)&blds[BBYTE(cur,0,s,ntp*2+ntl) + lane*16];
        Bm[ntl] = *(const half8*)&blds[BBYTE(cur,1,s,ntp*2+ntl) + lane*16];
      }
      __builtin_amdgcn_s_setprio(1);
#pragma unroll
      for(int ntl=0;ntl<2;ntl++){
        c0[ntl] = __builtin_amdgcn_mfma_f32_16x16x32_f16(ah, Bh[ntl], c0[ntl], 0,0,0);
        c1[ntl] = __builtin_amdgcn_mfma_f32_16x16x32_f16(ah, Bm[ntl], c1[ntl], 0,0,0);
        c1[ntl] = __builtin_amdgcn_mfma_f32_16x16x32_f16(am, Bh[ntl], c1[ntl], 0,0,0);
        c2[ntl] = __builtin_amdgcn_mfma_f32_16x16x32_f16(am, Bm[ntl], c2[ntl], 0,0,0);
      }
      __builtin_amdgcn_s_setprio(0);
    }
    if(more && tid < 256) stage(nb, ga);
    if(i & 1){
      // Kahan flush of the completed 128-k window (identical order to R1 -> bit-identical)
#pragma unroll
      for(int c=0;c<2;c++)
#pragma unroll
        for(int r=0;r<4;r++){
          const float v = c0[c][r] + c1[c][r]*C1 + c2[c][r]*C2;
          const float y = v - kcmp[c][r];
          const float t = ksum[c][r] + y;
          kcmp[c][r] = (t - ksum[c][r]) - y;
          ksum[c][r] = t;
        }
    }
    __syncthreads();
  }

  // epilogue: C layout col=lane&15 (expert), row=(lane>>4)*4+r (token); undo W scale
#pragma unroll
  for(int ntl=0;ntl<2;ntl++)
#pragma unroll
    for(int r=0;r<4;r++){
      const int tok = mtp*16 + (lane>>4)*4 + r;
      const int e = (ntp*2+ntl)*16 + (lane&15);
      const float lg = (ksum[ntl][r] - kcmp[ntl][r]) * INV_WS;
      lgout[(size_t)(tb+tok)*NE + eb + e] = lg;
    }
}

// Gating, 1 token per wave, grid T/4.
__global__ __launch_bounds__(256)
void gate(const float* __restrict__ lg, const float* __restrict__ bias,
          float* __restrict__ out, int T){
  const int tid = threadIdx.x, lane = tid & 63, wv = tid >> 6;
  const int t = blockIdx.x*4 + wv;
  const float4 bias4 = *(const float4*)(bias + 4*lane);
  const int g = lane >> 3;
  const float NEG_INF = -__builtin_inff();

  const float4 l4 = *(const float4*)(lg + (size_t)t*NE + 4*lane);
  float4 r4;   // uncorrected sigmoid scores
  r4.x = 1.f/(1.f + expf(-l4.x));
  r4.y = 1.f/(1.f + expf(-l4.y));
  r4.z = 1.f/(1.f + expf(-l4.z));
  r4.w = 1.f/(1.f + expf(-l4.w));
  float4 s4;   // corrected
  s4.x = r4.x + bias4.x; s4.y = r4.y + bias4.y;
  s4.z = r4.z + bias4.z; s4.w = r4.w + bias4.w;

  float m1 = s4.x, m2 = NEG_INF;
  if (s4.y > m1) { m2 = m1; m1 = s4.y; } else if (s4.y > m2) m2 = s4.y;
  if (s4.z > m1) { m2 = m1; m1 = s4.z; } else if (s4.z > m2) m2 = s4.z;
  if (s4.w > m1) { m2 = m1; m1 = s4.w; } else if (s4.w > m2) m2 = s4.w;
#pragma unroll
  for (int m = 1; m <= 4; m <<= 1) {
    const float o1 = __shfl_xor(m1, m);
    const float o2 = __shfl_xor(m2, m);
    const float nm1 = fmaxf(m1, o1);
    const float nm2 = fmaxf(fminf(m1, o1), fmaxf(m2, o2));
    m1 = nm1; m2 = nm2;
  }
  const float gs = m1 + m2;

  float gsv[8];
#pragma unroll
  for (int j = 0; j < 8; ++j) gsv[j] = __shfl(gs, j * 8);

  unsigned gm = 0;
#pragma unroll
  for (int r = 0; r < TOPKG; ++r) {
    float best = NEG_INF; int bj = 0;
#pragma unroll
    for (int j = 0; j < 8; ++j) {
      const bool avail = !((gm >> j) & 1u);
      if (avail && gsv[j] > best) { best = gsv[j]; bj = j; }
    }
    gm |= 1u << bj;
  }
  const bool allowed = (gm >> g) & 1u;

  float v0 = allowed ? s4.x : 0.f;
  float v1 = allowed ? s4.y : 0.f;
  float v2 = allowed ? s4.z : 0.f;
  float v3 = allowed ? s4.w : 0.f;

  float sumw = 0.f;
  int myidx = 0; float myraw = 0.f;
#pragma unroll
  for (int r = 0; r < TOPK; ++r) {
    float bv = v0; int bj = 0;
    if (v1 > bv) { bv = v1; bj = 1; }
    if (v2 > bv) { bv = v2; bj = 2; }
    if (v3 > bv) { bv = v3; bj = 3; }
    int bidx = 4 * lane + bj;
#pragma unroll
    for (int m = 1; m < 64; m <<= 1) {
      const float ov = __shfl_xor(bv, m);
      const int   oi = __shfl_xor(bidx, m);
      if (ov > bv || (ov == bv && oi < bidx)) { bv = ov; bidx = oi; }
    }
    const int oj = bidx & 3;
    const float cand = (oj == 0) ? r4.x
                     : (oj == 1) ? r4.y
                     : (oj == 2) ? r4.z
                     :             r4.w;
    const float raw = __shfl(cand, bidx >> 2);
    sumw += raw;
    if (lane == r) { myidx = bidx; myraw = raw; }
    if (lane == (bidx >> 2)) {
      if      (oj == 0) v0 = NEG_INF;
      else if (oj == 1) v1 = NEG_INF;
      else if (oj == 2) v2 = NEG_INF;
      else              v3 = NEG_INF;
    }
  }

  if (lane < TOPK) {
    out[(size_t)t * TOPK + lane] = (float)myidx;
    out[(size_t)T * TOPK + (size_t)t * TOPK + lane] = myraw / (sumw + 1e-20f) * 2.5f;
  }
}

extern "C" void kernel_launch(void* const* d_in, const int* in_sizes, int n_in,
                              void* d_out, int out_size, void* d_ws, size_t ws_size,
                              hipStream_t stream) {
  const float* hs   = (const float*)d_in[0];
  const float* wgt  = (const float*)d_in[1];
  const float* bias = (const float*)d_in[2];
  float* out = (float*)d_out;

  const int T = in_sizes[0] / HH;   // 8192

  unsigned short* bh = (unsigned short*)d_ws;
  unsigned short* bm = bh + (size_t)NE*HH;
  float* lgbuf = (float*)(bm + (size_t)NE*HH);   // 8.4 MB; total ws use 15.7 MB

  hipLaunchKernelGGL(prep_w, dim3(896), dim3(256), 0, stream, wgt, bh, bm);
  hipLaunchKernelGGL(gemm,   dim3(512), dim3(512), 0, stream, hs, bh, bm, lgbuf);
  hipLaunchKernelGGL(gate,   dim3(T/4), dim3(256), 0, stream, lgbuf, bias, out, T);
}

// Round 3
// 456.842 us; speedup vs baseline: 1.0898x; 1.0018x over previous
//
#include <hip/hip_runtime.h>
#include <cmath>

typedef __attribute__((ext_vector_type(8))) _Float16 half8;
typedef __attribute__((ext_vector_type(8))) unsigned short ushort8;
typedef __attribute__((ext_vector_type(4))) float f32x4;

#define HH 7168
#define NE 256
#define NQ 224        // K32 chunks
#define NWND 56       // 128-K windows
#define TOPK 8
#define TOPKG 4
#define WSC 1024.f
#define INV_WS (1.f/1024.f)
#define C1 (1.f/2048.f)       // 2^-11
#define C2 (1.f/4194304.f)    // 2^-22

// 2-level f16 split: x = h + m*2^-11, residual ~2^-25|x|
__device__ __forceinline__ void split2(float x, unsigned short& h, unsigned short& m){
  const _Float16 hh = (_Float16)x;
  const float r = x - (float)hh;                 // exact
  const _Float16 mm = (_Float16)(r * 2048.f);
  h = __builtin_bit_cast(unsigned short, hh);
  m = __builtin_bit_cast(unsigned short, mm);
}

// W*1024 -> (h,m) f16 in MFMA B-fragment order, coalesced writes.
// slot(q,nt,L) holds B[k=32q+8(L>>4)+j][e=16nt+(L&15)], j=0..7.
__global__ __launch_bounds__(256) void prep_w(const float* __restrict__ wgt,
                                              unsigned short* __restrict__ bh,
                                              unsigned short* __restrict__ bm){
  const int b = blockIdx.x;                 // 896 = 16 nt * 56 q-groups
  const int nt = b & 15, qb = (b >> 4) * 4;
  const int w = threadIdx.x >> 6, L = threadIdx.x & 63;
  const int q = qb + w;
  const int e = nt*16 + (L & 15);
  const int k0 = 32*q + 8*(L >> 4);
  const float4 a0 = *(const float4*)(wgt + (size_t)e*HH + k0);
  const float4 a1 = *(const float4*)(wgt + (size_t)e*HH + k0 + 4);
  const float v[8] = {a0.x,a0.y,a0.z,a0.w,a1.x,a1.y,a1.z,a1.w};
  ushort8 h8, m8;
#pragma unroll
  for(int j=0;j<8;j++){ unsigned short hh,mm; split2(v[j]*WSC, hh, mm); h8[j]=hh; m8[j]=mm; }
  const size_t base = ((size_t)(q*16+nt)*64 + L)*8;
  *(ushort8*)(bh+base) = h8;
  *(ushort8*)(bm+base) = m8;
}

// ---------------- GEMM: 4-phase counted-vmcnt pipeline ----------------
// Block = 32 tok x 128 exp (slice), 512 thr / 8 waves (2mt x 4nt), K-step 32.
// B: 3-buffer LDS ring, glds16 issued 2 iters ahead; raw s_barrier with exact
// counted vmcnt (ledger below) -- no full drains in the main loop (T3+T4).
// A: gloads at phase 0 for window w+1 (2000cy cover), split2+swizzled ds_write
// at phase 2 into a 2-deep A ring; staging VALU overlaps the MFMA pipe.
// vmcnt ledger (per wave, uniform): phase issues 2 B-glds; phase 0 adds 2 A-gloads.
//   end p0: [Bprev x2 retired | Bp0 x2, A x2 in flight]  -> vmcnt(4)
//   end p1: [Bp0 x2 retired   | A x2, Bp1 x2]            -> vmcnt(4)
//   end p2: [A consumed, Bp1 retired | Bp2 x2]           -> vmcnt(2) + lgkm(0) (A ds_writes)
//   end p3: [Bp2 retired | Bp3 x2]                       -> vmcnt(2)
// peel (no A): 2 / 2 / 0 / none.
#define AB(aw,lvl,mt,q,row) (((((aw)*4+(lvl)*2+(mt))*4+(q))*64+(row))*16)
__device__ __forceinline__ int swz(int bo){ return bo ^ (((bo >> 8) & 7) << 4); }

__device__ __forceinline__ void glds16(const void* g, void* l){
  __builtin_amdgcn_global_load_lds(
      (const __attribute__((address_space(1))) unsigned int*)g,
      (__attribute__((address_space(3))) unsigned int*)l, 16, 0, 0);
}

#define BAR_V4  do{ asm volatile("s_waitcnt vmcnt(4)" ::: "memory"); __builtin_amdgcn_s_barrier(); __builtin_amdgcn_sched_barrier(0); }while(0)
#define BAR_V2  do{ asm volatile("s_waitcnt vmcnt(2)" ::: "memory"); __builtin_amdgcn_s_barrier(); __builtin_amdgcn_sched_barrier(0); }while(0)
#define BAR_V2L do{ asm volatile("s_waitcnt lgkmcnt(0)\n\ts_waitcnt vmcnt(2)" ::: "memory"); __builtin_amdgcn_s_barrier(); __builtin_amdgcn_sched_barrier(0); }while(0)
#define BAR_V0  do{ asm volatile("s_waitcnt vmcnt(0)" ::: "memory"); __builtin_amdgcn_s_barrier(); __builtin_amdgcn_sched_barrier(0); }while(0)

#define KAHAN do{ \
  _Pragma("unroll") \
  for(int cc=0;cc<2;cc++) \
    _Pragma("unroll") \
    for(int r=0;r<4;r++){ \
      const float v = c0[cc][r] + c1[cc][r]*C1 + c2[cc][r]*C2; \
      const float y = v - kcmp[cc][r]; \
      const float t = ksum[cc][r] + y; \
      kcmp[cc][r] = (t - ksum[cc][r]) - y; \
      ksum[cc][r] = t; \
    } \
}while(0)

__global__ __launch_bounds__(512,4)
void gemm(const float* __restrict__ hs,
          const unsigned short* __restrict__ bhp,
          const unsigned short* __restrict__ bmp,
          float* __restrict__ lgout){
  __shared__ __align__(16) unsigned char blds[49152];  // 3buf x 2lvl x 8nt x 1KB
  __shared__ __align__(16) unsigned char alds[32768];  // 2win x 2lvl x 2mt x 4q x 64row x 16B

  const int tid = threadIdx.x, lane = tid & 63, w = tid >> 6;
  const int b = blockIdx.x;
  const int slice = (b >> 2) & 1;          // XCD 0-3 -> slice0, 4-7 -> slice1 (L2-resident)
  const int tg = (b >> 3)*4 + (b & 3);     // 0..255
  const int tb = tg*32, eb = slice*128;
  const int mtp = w >> 2, ntp = w & 3;

  f32x4 ksum[2], kcmp[2], c0[2], c1[2], c2[2];
#pragma unroll
  for(int cc=0;cc<2;cc++){ ksum[cc]=f32x4{0,0,0,0}; kcmp[cc]=f32x4{0,0,0,0}; }

  // A staging ids: 16 thr/token, thread covers 8 consecutive k of a 128-K window
  const int tokS = tid >> 4, kidx = tid & 15;
  const int mtS = tokS >> 4, m16S = tokS & 15;
  const int qS = kidx >> 2, kgS = kidx & 3;
  const int rowS = kgS*16 + m16S;
  const float* agp = hs + (size_t)(tb + tokS)*HH + kidx*8;
  float4 ga[2];

  auto stage = [&](int aw){
    unsigned short h[8], m[8];
    const float* gv = (const float*)ga;
#pragma unroll
    for(int p=0;p<8;p++) split2(gv[p], h[p], m[p]);
    ushort8 h8, m8;
#pragma unroll
    for(int j=0;j<8;j++){ h8[j]=h[j]; m8[j]=m[j]; }
    *(ushort8*)&alds[swz(AB(aw,0,mtS,qS,rowS))] = h8;
    *(ushort8*)&alds[swz(AB(aw,1,mtS,qS,rowS))] = m8;
  };

  // B issue: wave w owns slots (lvl = w>>2, nt = (w&3)*2 .. +1), 2 glds/phase
  const unsigned short* bsrc = (w >= 4 ? bmp : bhp)
      + ((size_t)((slice*8 + (w&3)*2)*64 + lane))*8;
  const int bdst = (w>>2)*8192 + (w&3)*2048;
  auto issueB = [&](int bufoff, int qpre){
    const unsigned short* s0 = bsrc + (size_t)qpre*8192;
    glds16(s0,       &blds[bufoff + bdst]);
    glds16(s0 + 512, &blds[bufoff + bdst + 1024]);
  };

  auto compute = [&](int awr, int q, int bc){
    const half8 ah = *(const half8*)&alds[swz(AB(awr,0,mtp,q,lane))];
    const half8 am = *(const half8*)&alds[swz(AB(awr,1,mtp,q,lane))];
    half8 Bh[2], Bm[2];
#pragma unroll
    for(int ntl=0;ntl<2;ntl++){
      Bh[ntl] = *(const half8*)&blds[bc + (ntp*2+ntl)*1024 + lane*16];
      Bm[ntl] = *(const half8*)&blds[bc + 8192 + (ntp*2+ntl)*1024 + lane*16];
    }
    __builtin_amdgcn_s_setprio(1);
#pragma unroll
    for(int ntl=0;ntl<2;ntl++){
      c0[ntl] = __builtin_amdgcn_mfma_f32_16x16x32_f16(ah, Bh[ntl], c0[ntl], 0,0,0);
      c1[ntl] = __builtin_amdgcn_mfma_f32_16x16x32_f16(ah, Bm[ntl], c1[ntl], 0,0,0);
      c1[ntl] = __builtin_amdgcn_mfma_f32_16x16x32_f16(am, Bh[ntl], c1[ntl], 0,0,0);
      c2[ntl] = __builtin_amdgcn_mfma_f32_16x16x32_f16(am, Bm[ntl], c2[ntl], 0,0,0);
    }
    __builtin_amdgcn_s_setprio(0);
  };

  // ---- prologue: A window 0 + B(0),B(1); queue [A x2, B0 x2, B1 x2]
  ga[0] = *(const float4*)agp; ga[1] = *(const float4*)(agp+4);
  issueB(0,     0);
  issueB(16384, 1);
  stage(0);                                   // consumes ga -> compiler waits vmcnt(4)
  asm volatile("s_waitcnt lgkmcnt(0)\n\ts_waitcnt vmcnt(2)" ::: "memory"); // B(0) landed
  __builtin_amdgcn_s_barrier();
  __builtin_amdgcn_sched_barrier(0);

  int bc = 0;   // invariant: bc = (i%3)*16384 at iter i
#pragma unroll 1
  for(int wnd=0; wnd<NWND-1; ++wnd){
    const int i0 = wnd*4;
    const int awr = wnd & 1, aws = awr ^ 1;
    int bp;
    // phase 0: issue B(i0+2) + A-gloads(wnd+1); zero window accum
    bp = bc + 32768; if(bp >= 49152) bp -= 49152;
    issueB(bp, i0+2);
    { const float* ap = agp + (size_t)(wnd+1)*128;
      ga[0] = *(const float4*)ap; ga[1] = *(const float4*)(ap+4); }
#pragma unroll
    for(int cc=0;cc<2;cc++){ c0[cc]=f32x4{0,0,0,0}; c1[cc]=f32x4{0,0,0,0}; c2[cc]=f32x4{0,0,0,0}; }
    compute(awr, 0, bc);
    BAR_V4;
    bc += 16384; if(bc == 49152) bc = 0;
    // phase 1
    bp = bc + 32768; if(bp >= 49152) bp -= 49152;
    issueB(bp, i0+3);
    compute(awr, 1, bc);
    BAR_V4;
    bc += 16384; if(bc == 49152) bc = 0;
    // phase 2: stage A(wnd+1) after MFMAs; lgkm drain before barrier
    bp = bc + 32768; if(bp >= 49152) bp -= 49152;
    issueB(bp, i0+4);
    compute(awr, 2, bc);
    stage(aws);
    BAR_V2L;
    bc += 16384; if(bc == 49152) bc = 0;
    // phase 3: Kahan flush of this 128-K window (identical order -> bit-identical)
    bp = bc + 32768; if(bp >= 49152) bp -= 49152;
    issueB(bp, i0+5);
    compute(awr, 3, bc);
    KAHAN;
    BAR_V2;
    bc += 16384; if(bc == 49152) bc = 0;
  }
  // ---- peeled last window (wnd=55, awr=1): no A traffic, B tail 222/223
  {
    int bp;
    // phase 0 (i=220): issue B(222)
    bp = bc + 32768; if(bp >= 49152) bp -= 49152;
    issueB(bp, 222);
#pragma unroll
    for(int cc=0;cc<2;cc++){ c0[cc]=f32x4{0,0,0,0}; c1[cc]=f32x4{0,0,0,0}; c2[cc]=f32x4{0,0,0,0}; }
    compute(1, 0, bc);
    BAR_V2;                                  // [B221 retired | B222 x2]
    bc += 16384; if(bc == 49152) bc = 0;
    // phase 1 (i=221): issue B(223)
    bp = bc + 32768; if(bp >= 49152) bp -= 49152;
    issueB(bp, 223);
    compute(1, 1, bc);
    BAR_V2;                                  // [B222 retired | B223 x2]
    bc += 16384; if(bc == 49152) bc = 0;
    // phase 2 (i=222): nothing to issue
    compute(1, 2, bc);
    BAR_V0;                                  // [B223 retired]
    bc += 16384; if(bc == 49152) bc = 0;
    // phase 3 (i=223): final
    compute(1, 3, bc);
    KAHAN;
  }

  // epilogue: C layout col=lane&15 (expert), row=(lane>>4)*4+r (token); undo W scale
#pragma unroll
  for(int ntl=0;ntl<2;ntl++)
#pragma unroll
    for(int r=0;r<4;r++){
      const int tok = mtp*16 + (lane>>4)*4 + r;
      const int e = (ntp*2+ntl)*16 + (lane&15);
      const float lg = (ksum[ntl][r] - kcmp[ntl][r]) * INV_WS;
      lgout[(size_t)(tb+tok)*NE + eb + e] = lg;
    }
}

// Gating, 1 token per wave, grid T/4.
__global__ __launch_bounds__(256)
void gate(const float* __restrict__ lg, const float* __restrict__ bias,
          float* __restrict__ out, int T){
  const int tid = threadIdx.x, lane = tid & 63, wv = tid >> 6;
  const int t = blockIdx.x*4 + wv;
  const float4 bias4 = *(const float4*)(bias + 4*lane);
  const int g = lane >> 3;
  const float NEG_INF = -__builtin_inff();

  const float4 l4 = *(const float4*)(lg + (size_t)t*NE + 4*lane);
  float4 r4;   // uncorrected sigmoid scores
  r4.x = 1.f/(1.f + expf(-l4.x));
  r4.y = 1.f/(1.f + expf(-l4.y));
  r4.z = 1.f/(1.f + expf(-l4.z));
  r4.w = 1.f/(1.f + expf(-l4.w));
  float4 s4;   // corrected
  s4.x = r4.x + bias4.x; s4.y = r4.y + bias4.y;
  s4.z = r4.z + bias4.z; s4.w = r4.w + bias4.w;

  float m1 = s4.x, m2 = NEG_INF;
  if (s4.y > m1) { m2 = m1; m1 = s4.y; } else if (s4.y > m2) m2 = s4.y;
  if (s4.z > m1) { m2 = m1; m1 = s4.z; } else if (s4.z > m2) m2 = s4.z;
  if (s4.w > m1) { m2 = m1; m1 = s4.w; } else if (s4.w > m2) m2 = s4.w;
#pragma unroll
  for (int m = 1; m <= 4; m <<= 1) {
    const float o1 = __shfl_xor(m1, m);
    const float o2 = __shfl_xor(m2, m);
    const float nm1 = fmaxf(m1, o1);
    const float nm2 = fmaxf(fminf(m1, o1), fmaxf(m2, o2));
    m1 = nm1; m2 = nm2;
  }
  const float gs = m1 + m2;

  float gsv[8];
#pragma unroll
  for (int j = 0; j < 8; ++j) gsv[j] = __shfl(gs, j * 8);

  unsigned gm = 0;
#pragma unroll
  for (int r = 0; r < TOPKG; ++r) {
    float best = NEG_INF; int bj = 0;
#pragma unroll
    for (int j = 0; j < 8; ++j) {
      const bool avail = !((gm >> j) & 1u);
      if (avail && gsv[j] > best) { best = gsv[j]; bj = j; }
    }
    gm |= 1u << bj;
  }
  const bool allowed = (gm >> g) & 1u;

  float v0 = allowed ? s4.x : 0.f;
  float v1 = allowed ? s4.y : 0.f;
  float v2 = allowed ? s4.z : 0.f;
  float v3 = allowed ? s4.w : 0.f;

  float sumw = 0.f;
  int myidx = 0; float myraw = 0.f;
#pragma unroll
  for (int r = 0; r < TOPK; ++r) {
    float bv = v0; int bj = 0;
    if (v1 > bv) { bv = v1; bj = 1; }
    if (v2 > bv) { bv = v2; bj = 2; }
    if (v3 > bv) { bv = v3; bj = 3; }
    int bidx = 4 * lane + bj;
#pragma unroll
    for (int m = 1; m < 64; m <<= 1) {
      const float ov = __shfl_xor(bv, m);
      const int   oi = __shfl_xor(bidx, m);
      if (ov > bv || (ov == bv && oi < bidx)) { bv = ov; bidx = oi; }
    }
    const int oj = bidx & 3;
    const float cand = (oj == 0) ? r4.x
                     : (oj == 1) ? r4.y
                     : (oj == 2) ? r4.z
                     :             r4.w;
    const float raw = __shfl(cand, bidx >> 2);
    sumw += raw;
    if (lane == r) { myidx = bidx; myraw = raw; }
    if (lane == (bidx >> 2)) {
      if      (oj == 0) v0 = NEG_INF;
      else if (oj == 1) v1 = NEG_INF;
      else if (oj == 2) v2 = NEG_INF;
      else              v3 = NEG_INF;
    }
  }

  if (lane < TOPK) {
    out[(size_t)t * TOPK + lane] = (float)myidx;
    out[(size_t)T * TOPK + (size_t)t * TOPK + lane] = myraw / (sumw + 1e-20f) * 2.5f;
  }
}

extern "C" void kernel_launch(void* const* d_in, const int* in_sizes, int n_in,
                              void* d_out, int out_size, void* d_ws, size_t ws_size,
                              hipStream_t stream) {
  const float* hs   = (const float*)d_in[0];
  const float* wgt  = (const float*)d_in[1];
  const float* bias = (const float*)d_in[2];
  float* out = (float*)d_out;

  const int T = in_sizes[0] / HH;   // 8192

  unsigned short* bh = (unsigned short*)d_ws;
  unsigned short* bm = bh + (size_t)NE*HH;
  float* lgbuf = (float*)(bm + (size_t)NE*HH);   // 8.4 MB; total ws use 15.7 MB

  hipLaunchKernelGGL(prep_w, dim3(896), dim3(256), 0, stream, wgt, bh, bm);
  hipLaunchKernelGGL(gemm,   dim3(512), dim3(512), 0, stream, hs, bh, bm, lgbuf);
  hipLaunchKernelGGL(gate,   dim3(T/4), dim3(256), 0, stream, lgbuf, bias, out, T);
}